// Round 1
// baseline (1625.713 us; speedup 1.0000x reference)
//
#include <hip/hip_runtime.h>

typedef __attribute__((ext_vector_type(8))) short short8;
typedef __attribute__((ext_vector_type(4))) float f32x4;
typedef __attribute__((ext_vector_type(2))) unsigned int u32x2;

#define TTOK 10000

__device__ __forceinline__ unsigned pkbf(float lo, float hi){
  unsigned r;
  asm("v_cvt_pk_bf16_f32 %0, %1, %2" : "=v"(r) : "v"(lo), "v"(hi));
  return r;
}

__device__ __forceinline__ unsigned short f2b(float f){
  unsigned x = __float_as_uint(f);
  unsigned r = (x + 0x7fffu + ((x>>16)&1u)) >> 16; // RNE
  return (unsigned short)r;
}

// ---------------- prep: bf16 weights, hb+t*tw seeds, c vector ----------------
__global__ void cnf_prep(const float* __restrict__ h, const float* __restrict__ Wx,
                         const float* __restrict__ wxt, const float* __restrict__ bx,
                         const float* __restrict__ Wh, const float* __restrict__ wht,
                         const float* __restrict__ bh, const float* __restrict__ W2,
                         float* __restrict__ hbt, float* __restrict__ cv,
                         unsigned short* __restrict__ wxb, unsigned short* __restrict__ w2b)
{
  const int b = blockIdx.x, t = threadIdx.x;
  if (b < 8) {
    for (int i=0;i<8;++i){ int idx = b*2048 + i*256 + t; wxb[idx] = f2b(Wx[idx]); }
  } else if (b < 16) {
    for (int i=0;i<8;++i){ int idx = (b-8)*2048 + i*256 + t; w2b[idx] = f2b(W2[idx]); }
  } else if (b < 18) {
    for (int i=0;i<4;++i){
      int idx = i*256 + t;
      int sb = (b-16)*8 + (idx>>7);
      int j  = idx & 127;
      float a = 0.f;
      for (int e2=0;e2<128;++e2) a += h[sb*128+e2]*Wh[j*128+e2];
      float base = a + bh[j] + bx[j];
      float tw   = wxt[j] + wht[j];
      for (int ti=0; ti<5; ++ti)
        hbt[(ti*16+sb)*128 + j] = base + 0.25f*(float)ti*tw;   // t in {0,.25,.5,.75,1}
    }
  } else {
    if (t < 128){
      float a = 0.f;
      for (int i=0;i<128;++i) a += W2[i*128+t]*Wx[t*128+i];
      cv[t] = a;
    }
  }
}

// ---------------- fused CNF main kernel ----------------
// Block: 256 thr = 4 waves; wave handles 32 rows (2 N-tiles of 16).
// Transposed MFMA formulation: preT[h,m] = sum_e Wx[h,e]*zT[e,m] (A=Wx, B=zT).
// C-layout (m = lane&15 fixed) -> bf16 B-frags via per-wave 2KB LDS transpose.
__global__ __launch_bounds__(256, 2) void cnf_main(
    const float* __restrict__ emb, const float* __restrict__ lp0,
    const float* __restrict__ b2g, const float* __restrict__ hbt,
    const float* __restrict__ cg,  const unsigned short* __restrict__ wxb,
    const unsigned short* __restrict__ w2b, float* __restrict__ out)
{
  __shared__ __align__(16) unsigned short sWx[16384];
  __shared__ __align__(16) unsigned short sW2[16384];
  __shared__ __align__(16) float sC[128];
  __shared__ __align__(16) float sB2[128];
  __shared__ __align__(16) unsigned short sT[4][1024]; // per-wave transpose buf (2KB)

  const int tid = threadIdx.x;

  // stage weights into LDS with XOR swizzle (row&7)<<4 to kill b128-read bank conflicts
  for (int it=0; it<8; ++it){
    int L = it*4096 + tid*16;          // byte offset, 16B chunk inside one 256B row
    int hrow = L >> 8;
    int dst = L ^ ((hrow&7)<<4);
    *(int4*)((char*)sWx + dst) = *(const int4*)((const char*)wxb + L);
    *(int4*)((char*)sW2 + dst) = *(const int4*)((const char*)w2b + L);
  }
  if (tid < 128) sC[tid] = cg[tid]; else sB2[tid-128] = b2g[tid-128];
  __syncthreads();

  const int w = tid>>6, l = tid&63, q = l&15, g = l>>4;
  unsigned short* tb = &sT[w][0];
  const int cw  = q*8 + 4*(g&1) + 128*(g>>1); // transpose write base (ushort idx), + htl*256
  const int cr  = g*128 + q*8;                // transpose read base, + kcl*512
  const int wsw = (q&7)<<4;                   // weight-read swizzle
  const int qg  = q*256 + g*16;               // weight-read lane offset (bytes)

  const int rowa = blockIdx.x*128 + 32*w + q;
  int row[2] = {rowa, rowa+16};
  int sb[2], tt[2];
  sb[0] = row[0]/TTOK; tt[0] = row[0]-sb[0]*TTOK;
  sb[1] = row[1]/TTOK; tt[1] = row[1]-sb[1]*TTOK;

  f32x4 zb[2][8], ks[2][8], wk[2][8];
  float dlt[2] = {0.f, 0.f};

  // z0 = emb[t] into fp32 C-layout masters (slot e = 16*ht+4*g+r, col q)
  #pragma unroll
  for (int nt=0; nt<2; ++nt)
    #pragma unroll
    for (int ht=0; ht<8; ++ht){
      zb[nt][ht] = *(const f32x4*)(emb + tt[nt]*128 + 16*ht + 4*g);
      wk[nt][ht] = (f32x4){0.f,0.f,0.f,0.f};
      ks[nt][ht] = (f32x4){0.f,0.f,0.f,0.f};
    }

  #pragma unroll 1
  for (int se=0; se<8; ++se){
    const int   s    = se>>2, e = se&3;
    const float coef = (e==0)?0.f:((e==3)?0.5f:0.25f); // z_eval = z_base + coef*k_prev
    const float we   = (e==1||e==2)?2.f:1.f;
    const int   ti   = 2*s + ((e==0)?0:((e<3)?1:2));

    // ---- pack z_eval -> LDS transpose -> bf16 B-frags
    short8 zfr[2][4];
    #pragma unroll
    for (int nt=0; nt<2; ++nt){
      #pragma unroll
      for (int hf=0; hf<2; ++hf){
        #pragma unroll
        for (int htl=0; htl<4; ++htl){
          const int ht = 4*hf + htl;
          float v0 = zb[nt][ht][0] + coef*wk[nt][ht][0];
          float v1 = zb[nt][ht][1] + coef*wk[nt][ht][1];
          float v2 = zb[nt][ht][2] + coef*wk[nt][ht][2];
          float v3 = zb[nt][ht][3] + coef*wk[nt][ht][3];
          u32x2 wv = { pkbf(v0,v1), pkbf(v2,v3) };
          *(u32x2*)&tb[htl*256 + cw] = wv;
        }
        #pragma unroll
        for (int kcl=0; kcl<2; ++kcl)
          zfr[nt][2*hf+kcl] = *(const short8*)&tb[kcl*512 + cr];
      }
    }

    // ---- seed acc with hb + t*tw (global fp32, L2-resident)
    #pragma unroll
    for (int nt=0; nt<2; ++nt){
      const float* hb = hbt + (ti*16 + sb[nt])*128 + 4*g;
      #pragma unroll
      for (int ht=0; ht<8; ++ht)
        wk[nt][ht] = *(const f32x4*)(hb + 16*ht);
    }

    // ---- matmul1: pre = Wx . zT
    #pragma unroll
    for (int kc=0; kc<4; ++kc){
      #pragma unroll
      for (int ht=0; ht<8; ++ht){
        const int off = (ht*4096 + kc*64 + qg) ^ wsw;
        short8 af = *(const short8*)((const char*)sWx + off);
        wk[0][ht] = __builtin_amdgcn_mfma_f32_16x16x32_bf16(af, zfr[0][kc], wk[0][ht], 0,0,0);
        wk[1][ht] = __builtin_amdgcn_mfma_f32_16x16x32_bf16(af, zfr[1][kc], wk[1][ht], 0,0,0);
      }
    }

    // ---- elementwise: softplus -> bf16 frags (via LDS transpose), sigmoid*c -> div
    short8 sfr[2][4];
    float dv[2] = {0.f,0.f};
    #pragma unroll
    for (int nt=0; nt<2; ++nt){
      #pragma unroll
      for (int hf=0; hf<2; ++hf){
        #pragma unroll
        for (int htl=0; htl<4; ++htl){
          const int ht = 4*hf+htl;
          f32x4 cc = *(const f32x4*)(&sC[16*ht + 4*g]);
          float spv[4];
          #pragma unroll
          for (int r=0;r<4;++r){
            float x  = wk[nt][ht][r];
            float ax = __builtin_fabsf(x);
            float ea = __expf(-ax);
            float opa = 1.0f + ea;
            float rc = __builtin_amdgcn_rcpf(opa);
            float lg = __logf(opa);
            spv[r] = fmaxf(x,0.f) + lg;                 // softplus
            float sg = (x >= 0.f) ? rc : ea*rc;         // sigmoid
            dv[nt] += sg*cc[r];
          }
          u32x2 wv = { pkbf(spv[0],spv[1]), pkbf(spv[2],spv[3]) };
          *(u32x2*)&tb[htl*256 + cw] = wv;
        }
        #pragma unroll
        for (int kcl=0; kcl<2; ++kcl)
          sfr[nt][2*hf+kcl] = *(const short8*)&tb[kcl*512 + cr];
      }
      dlt[nt] += we*dv[nt];
    }

    // ---- matmul2: dz = W2 . spT  (acc seeded with b2)
    #pragma unroll
    for (int nt=0; nt<2; ++nt)
      #pragma unroll
      for (int ot=0; ot<8; ++ot)
        wk[nt][ot] = *(const f32x4*)(&sB2[16*ot + 4*g]);
    #pragma unroll
    for (int kc=0; kc<4; ++kc){
      #pragma unroll
      for (int ot=0; ot<8; ++ot){
        const int off = (ot*4096 + kc*64 + qg) ^ wsw;
        short8 af = *(const short8*)((const char*)sW2 + off);
        wk[0][ot] = __builtin_amdgcn_mfma_f32_16x16x32_bf16(af, sfr[0][kc], wk[0][ot], 0,0,0);
        wk[1][ot] = __builtin_amdgcn_mfma_f32_16x16x32_bf16(af, sfr[1][kc], wk[1][ot], 0,0,0);
      }
    }

    // ---- RK4 accumulate (wk now holds k_e; also feeds next eval's z_eval)
    if (e==0){
      #pragma unroll
      for (int nt=0;nt<2;++nt)
        #pragma unroll
        for (int ht=0;ht<8;++ht) ks[nt][ht] = wk[nt][ht];
    } else {
      #pragma unroll
      for (int nt=0;nt<2;++nt)
        #pragma unroll
        for (int ht=0;ht<8;++ht) ks[nt][ht] += we*wk[nt][ht];
    }
    if (e==3){
      #pragma unroll
      for (int nt=0;nt<2;++nt)
        #pragma unroll
        for (int ht=0;ht<8;++ht) zb[nt][ht] += (1.f/12.f)*ks[nt][ht];
    }
  }

  // ---- epilogue: reduce div partials over the 4 g-lanes, write log_pz1
  #pragma unroll
  for (int nt=0; nt<2; ++nt){
    float d = dlt[nt]*(1.f/12.f);
    d += __shfl_xor(d, 16, 64);
    d += __shfl_xor(d, 32, 64);
    if (g==0) out[row[nt]] = lp0[row[nt]] - d;
  }
}

extern "C" void kernel_launch(void* const* d_in, const int* in_sizes, int n_in,
                              void* d_out, int out_size, void* d_ws, size_t ws_size,
                              hipStream_t stream) {
  const float* h    = (const float*)d_in[0];
  const float* emb  = (const float*)d_in[1];
  const float* lp0  = (const float*)d_in[2];
  const float* Wx   = (const float*)d_in[3];
  const float* wxt  = (const float*)d_in[4];
  const float* bx   = (const float*)d_in[5];
  const float* Wh   = (const float*)d_in[6];
  const float* wht  = (const float*)d_in[7];
  const float* bh   = (const float*)d_in[8];
  const float* W2   = (const float*)d_in[9];
  const float* b2   = (const float*)d_in[10];
  float* out = (float*)d_out;

  char* ws = (char*)d_ws;
  float* hbt          = (float*)ws;            // 5*16*128 f32 = 40960 B
  float* cv           = (float*)(ws + 40960);  // 128 f32     = 512 B
  unsigned short* wxb = (unsigned short*)(ws + 41472); // 16384 bf16 = 32768 B
  unsigned short* w2b = (unsigned short*)(ws + 74240); // 16384 bf16 = 32768 B

  cnf_prep<<<19, 256, 0, stream>>>(h, Wx, wxt, bx, Wh, wht, bh, W2, hbt, cv, wxb, w2b);
  cnf_main<<<1250, 256, 0, stream>>>(emb, lp0, b2, hbt, cv, wxb, w2b, out);
}

// Round 2
// 323.485 us; speedup vs baseline: 5.0256x; 5.0256x over previous
//
#include <hip/hip_runtime.h>

typedef __attribute__((ext_vector_type(8))) short short8;
typedef __attribute__((ext_vector_type(4))) float f32x4;
typedef __attribute__((ext_vector_type(2))) unsigned int u32x2;

#define TTOK 10000

__device__ __forceinline__ unsigned pkbf(float lo, float hi){
  unsigned r;
  asm("v_cvt_pk_bf16_f32 %0, %1, %2" : "=v"(r) : "v"(lo), "v"(hi));
  return r;
}

__device__ __forceinline__ unsigned short f2b(float f){
  unsigned x = __float_as_uint(f);
  unsigned r = (x + 0x7fffu + ((x>>16)&1u)) >> 16; // RNE
  return (unsigned short)r;
}

// ---------------- prep: bf16 weights, hb+t*tw seeds, c vector ----------------
__global__ void cnf_prep(const float* __restrict__ h, const float* __restrict__ Wx,
                         const float* __restrict__ wxt, const float* __restrict__ bx,
                         const float* __restrict__ Wh, const float* __restrict__ wht,
                         const float* __restrict__ bh, const float* __restrict__ W2,
                         float* __restrict__ hbt, float* __restrict__ cv,
                         unsigned short* __restrict__ wxb, unsigned short* __restrict__ w2b)
{
  const int b = blockIdx.x, t = threadIdx.x;
  if (b < 8) {
    for (int i=0;i<8;++i){ int idx = b*2048 + i*256 + t; wxb[idx] = f2b(Wx[idx]); }
  } else if (b < 16) {
    for (int i=0;i<8;++i){ int idx = (b-8)*2048 + i*256 + t; w2b[idx] = f2b(W2[idx]); }
  } else if (b < 18) {
    for (int i=0;i<4;++i){
      int idx = i*256 + t;
      int sb = (b-16)*8 + (idx>>7);
      int j  = idx & 127;
      float a = 0.f;
      for (int e2=0;e2<128;++e2) a += h[sb*128+e2]*Wh[j*128+e2];
      float base = a + bh[j] + bx[j];
      float tw   = wxt[j] + wht[j];
      for (int ti=0; ti<5; ++ti)
        hbt[(ti*16+sb)*128 + j] = base + 0.25f*(float)ti*tw;   // t in {0,.25,.5,.75,1}
    }
  } else {
    if (t < 128){
      float a = 0.f;
      for (int i=0;i<128;++i) a += W2[i*128+t]*Wx[t*128+i];
      cv[t] = a;
    }
  }
}

// ---------------- fused CNF main kernel ----------------
// Block: 256 thr = 4 waves; wave handles 16 rows (one 16-wide N-tile).
// Transposed MFMA formulation: preT[h,m] = sum_e Wx[h,e]*zT[e,m] (A=Wx, B=zT).
// Per-thread state: zb/ks/wk = 96 f32 -> no spill (round-1 lesson: nt=2 spilled 4 GB).
__global__ __launch_bounds__(256, 2) void cnf_main(
    const float* __restrict__ emb, const float* __restrict__ lp0,
    const float* __restrict__ b2g, const float* __restrict__ hbt,
    const float* __restrict__ cg,  const unsigned short* __restrict__ wxb,
    const unsigned short* __restrict__ w2b, float* __restrict__ out)
{
  __shared__ __align__(16) unsigned short sWx[16384];
  __shared__ __align__(16) unsigned short sW2[16384];
  __shared__ __align__(16) float sC[128];
  __shared__ __align__(16) float sB2[128];
  __shared__ __align__(16) float sH[5*2*128];            // hb+t*tw slices for block's <=2 sb values
  __shared__ __align__(16) unsigned short sT[4][1024];   // per-wave transpose buf (2KB)

  const int tid = threadIdx.x;
  const int rowbase = blockIdx.x*64;
  const int sb0 = rowbase/TTOK, sb1 = (rowbase+63)/TTOK;

  // stage weights into LDS with XOR swizzle (row&7)<<4 to kill b128-read bank conflicts
  for (int it=0; it<8; ++it){
    int L = it*4096 + tid*16;          // byte offset, 16B chunk inside one 256B row
    int hrow = L >> 8;
    int dst = L ^ ((hrow&7)<<4);
    *(int4*)((char*)sWx + dst) = *(const int4*)((const char*)wxb + L);
    *(int4*)((char*)sW2 + dst) = *(const int4*)((const char*)w2b + L);
  }
  if (tid < 128) sC[tid] = cg[tid]; else sB2[tid-128] = b2g[tid-128];
  for (int idx = tid; idx < 1280; idx += 256){
    int ti = idx >> 8, r = idx & 255;
    int j = r >> 7, e = r & 127;
    int sb = j ? sb1 : sb0;
    sH[idx] = hbt[(ti*16 + sb)*128 + e];
  }
  __syncthreads();

  const int w = tid>>6, l = tid&63, q = l&15, g = l>>4;
  unsigned short* tb = &sT[w][0];
  const int cw  = q*8 + 4*(g&1) + 128*(g>>1); // transpose write base (ushort idx), + htl*256
  const int cr  = g*128 + q*8;                // transpose read base, + kcl*512
  const int wsw = (q&7)<<4;                   // weight-read swizzle
  const int qg  = q*256 + g*16;               // weight-read lane offset (bytes)

  const int row = rowbase + 16*w + q;
  const int sb  = row/TTOK, tt = row - sb*TTOK;
  const int hsel = (sb == sb0) ? 0 : 128;

  f32x4 zb[8], ks[8], wk[8];
  float dlt = 0.f;

  // z0 = emb[t] into fp32 C-layout masters (slot e = 16*ht+4*g+r, col q)
  #pragma unroll
  for (int ht=0; ht<8; ++ht){
    zb[ht] = *(const f32x4*)(emb + tt*128 + 16*ht + 4*g);
    wk[ht] = (f32x4){0.f,0.f,0.f,0.f};
    ks[ht] = (f32x4){0.f,0.f,0.f,0.f};
  }

  #pragma unroll 1
  for (int se=0; se<8; ++se){
    const int   s    = se>>2, e = se&3;
    const float coef = (e==0)?0.f:((e==3)?0.5f:0.25f); // z_eval = z_base + coef*k_prev
    const float we   = (e==1||e==2)?2.f:1.f;
    const int   ti   = 2*s + ((e==0)?0:((e<3)?1:2));

    // ---- pack z_eval -> LDS transpose -> bf16 B-frags
    short8 zfr[4];
    #pragma unroll
    for (int hf=0; hf<2; ++hf){
      #pragma unroll
      for (int htl=0; htl<4; ++htl){
        const int ht = 4*hf + htl;
        float v0 = zb[ht][0] + coef*wk[ht][0];
        float v1 = zb[ht][1] + coef*wk[ht][1];
        float v2 = zb[ht][2] + coef*wk[ht][2];
        float v3 = zb[ht][3] + coef*wk[ht][3];
        u32x2 wv = { pkbf(v0,v1), pkbf(v2,v3) };
        *(u32x2*)&tb[htl*256 + cw] = wv;
      }
      #pragma unroll
      for (int kcl=0; kcl<2; ++kcl)
        zfr[2*hf+kcl] = *(const short8*)&tb[kcl*512 + cr];
    }

    // ---- seed acc with hb + t*tw (LDS slice)
    {
      const float* hb = &sH[ti*256 + hsel + 4*g];
      #pragma unroll
      for (int ht=0; ht<8; ++ht)
        wk[ht] = *(const f32x4*)(hb + 16*ht);
    }

    // ---- matmul1: pre = Wx . zT
    #pragma unroll
    for (int kc=0; kc<4; ++kc){
      #pragma unroll
      for (int ht=0; ht<8; ++ht){
        const int off = (ht*4096 + kc*64 + qg) ^ wsw;
        short8 af = *(const short8*)((const char*)sWx + off);
        wk[ht] = __builtin_amdgcn_mfma_f32_16x16x32_bf16(af, zfr[kc], wk[ht], 0,0,0);
      }
    }

    // ---- elementwise: softplus -> bf16 frags (via LDS transpose), sigmoid*c -> div
    short8 sfr[4];
    float dv = 0.f;
    #pragma unroll
    for (int hf=0; hf<2; ++hf){
      #pragma unroll
      for (int htl=0; htl<4; ++htl){
        const int ht = 4*hf+htl;
        f32x4 cc = *(const f32x4*)(&sC[16*ht + 4*g]);
        float spv[4];
        #pragma unroll
        for (int r=0;r<4;++r){
          float x  = wk[ht][r];
          float ax = __builtin_fabsf(x);
          float ea = __expf(-ax);
          float opa = 1.0f + ea;
          float rc = __builtin_amdgcn_rcpf(opa);
          float lg = __logf(opa);
          spv[r] = fmaxf(x,0.f) + lg;                 // softplus
          float sg = (x >= 0.f) ? rc : ea*rc;         // sigmoid
          dv += sg*cc[r];
        }
        u32x2 wv = { pkbf(spv[0],spv[1]), pkbf(spv[2],spv[3]) };
        *(u32x2*)&tb[htl*256 + cw] = wv;
      }
      #pragma unroll
      for (int kcl=0; kcl<2; ++kcl)
        sfr[2*hf+kcl] = *(const short8*)&tb[kcl*512 + cr];
    }
    dlt += we*dv;

    // ---- matmul2: dz = W2 . spT  (acc seeded with b2)
    #pragma unroll
    for (int ot=0; ot<8; ++ot)
      wk[ot] = *(const f32x4*)(&sB2[16*ot + 4*g]);
    #pragma unroll
    for (int kc=0; kc<4; ++kc){
      #pragma unroll
      for (int ot=0; ot<8; ++ot){
        const int off = (ot*4096 + kc*64 + qg) ^ wsw;
        short8 af = *(const short8*)((const char*)sW2 + off);
        wk[ot] = __builtin_amdgcn_mfma_f32_16x16x32_bf16(af, sfr[kc], wk[ot], 0,0,0);
      }
    }

    // ---- RK4 accumulate (wk now holds k_e; also feeds next eval's z_eval)
    if (e==0){
      #pragma unroll
      for (int ht=0;ht<8;++ht) ks[ht] = wk[ht];
    } else {
      #pragma unroll
      for (int ht=0;ht<8;++ht) ks[ht] += we*wk[ht];
    }
    if (e==3){
      #pragma unroll
      for (int ht=0;ht<8;++ht) zb[ht] += (1.f/12.f)*ks[ht];
    }
  }

  // ---- epilogue: reduce div partials over the 4 g-lanes, write log_pz1
  {
    float d = dlt*(1.f/12.f);
    d += __shfl_xor(d, 16, 64);
    d += __shfl_xor(d, 32, 64);
    if (g==0) out[row] = lp0[row] - d;
  }
}

extern "C" void kernel_launch(void* const* d_in, const int* in_sizes, int n_in,
                              void* d_out, int out_size, void* d_ws, size_t ws_size,
                              hipStream_t stream) {
  const float* h    = (const float*)d_in[0];
  const float* emb  = (const float*)d_in[1];
  const float* lp0  = (const float*)d_in[2];
  const float* Wx   = (const float*)d_in[3];
  const float* wxt  = (const float*)d_in[4];
  const float* bx   = (const float*)d_in[5];
  const float* Wh   = (const float*)d_in[6];
  const float* wht  = (const float*)d_in[7];
  const float* bh   = (const float*)d_in[8];
  const float* W2   = (const float*)d_in[9];
  const float* b2   = (const float*)d_in[10];
  float* out = (float*)d_out;

  char* ws = (char*)d_ws;
  float* hbt          = (float*)ws;            // 5*16*128 f32 = 40960 B
  float* cv           = (float*)(ws + 40960);  // 128 f32     = 512 B
  unsigned short* wxb = (unsigned short*)(ws + 41472); // 16384 bf16 = 32768 B
  unsigned short* w2b = (unsigned short*)(ws + 74240); // 16384 bf16 = 32768 B

  cnf_prep<<<19, 256, 0, stream>>>(h, Wx, wxt, bx, Wh, wht, bh, W2, hbt, cv, wxb, w2b);
  cnf_main<<<2500, 256, 0, stream>>>(emb, lp0, b2, hbt, cv, wxb, w2b, out);
}